// Round 1
// baseline (277.967 us; speedup 1.0000x reference)
//
#include <hip/hip_runtime.h>

#define CCH 256
#define HWP 9216
#define IMGDIM 96

typedef __attribute__((ext_vector_type(8))) short s16x8;
typedef __attribute__((ext_vector_type(4))) float f32x4;

__device__ __forceinline__ unsigned short f2bf(float f){
  unsigned u = __float_as_uint(f);
  u += 0x7fffu + ((u >> 16) & 1u);
  return (unsigned short)(u >> 16);
}
__device__ __forceinline__ float bf2f(unsigned short h){
  return __uint_as_float(((unsigned)h) << 16);
}

// ---------------- K0: convert the two projection weights to bf16 ----------------
__global__ void k0_convert(const float* __restrict__ wx, const float* __restrict__ wp,
                           unsigned short* __restrict__ wxb, unsigned short* __restrict__ wpb){
  int i = blockIdx.x * 256 + threadIdx.x;   // 65536 total
  wxb[i] = f2bf(wx[i]);
  wpb[i] = f2bf(wp[i]);
}

// ---------------- shared GEMM core ----------------
// Computes a 256(o) x 64(p) tile: D = W(256x256) * X(256x64).
// A = wbf row-major [o][c] bf16 (global, L2-resident).
// B = lds tile, layout [p][c] bf16, byte addr swizzled:  addr ^= ((p&7)<<4).
// Same k-slot function (g*8+j) used for both operands -> any HW k-permutation cancels.
// C/D layout (m89-verified): col = lane&15, row = 4*(lane>>4) + reg.
__device__ __forceinline__ void gemm_core(const unsigned short* __restrict__ wbf,
                                          const unsigned short* lds_x,
                                          f32x4 acc[4][4], int lane, int obase){
  const int g = lane >> 4, r = lane & 15;
  #pragma unroll
  for (int k0 = 0; k0 < 256; k0 += 32){
    s16x8 afr[4], bfr[4];
    #pragma unroll
    for (int nf = 0; nf < 4; ++nf){
      int p = nf*16 + r;
      unsigned off = (unsigned)(p*512 + (k0 + g*8)*2) ^ ((unsigned)(p & 7) << 4);
      bfr[nf] = *(const s16x8*)((const char*)lds_x + off);
    }
    #pragma unroll
    for (int mf = 0; mf < 4; ++mf){
      afr[mf] = *(const s16x8*)(wbf + (size_t)(obase + mf*16 + r)*CCH + k0 + g*8);
    }
    #pragma unroll
    for (int mf = 0; mf < 4; ++mf){
      #pragma unroll
      for (int nf = 0; nf < 4; ++nf){
        acc[mf][nf] = __builtin_amdgcn_mfma_f32_16x16x32_bf16(afr[mf], bfr[nf], acc[mf][nf], 0, 0, 0);
      }
    }
  }
}

// ---------------- K1: xp = w_xproj * x (+bias), plus xbar partial sums ----------------
// Output xp stored as [b][p][o] bf16.  xpart[b][9][16][256] fp32 partial bin sums.
__global__ __launch_bounds__(256) void k1_xproj(const float* __restrict__ x,
    const unsigned short* __restrict__ wxb, const float* __restrict__ bx,
    unsigned short* __restrict__ xp, float* __restrict__ xpart){
  const int tile = blockIdx.x, b = blockIdx.y;
  const int p0 = tile * 64;
  const int t = threadIdx.x;
  const int lane = t & 63, wave = t >> 6;
  __shared__ __align__(16) unsigned short xlds[64*256];

  const float* xb = x + (size_t)b * CCH * HWP;
  const int binj = p0 >> 10;          // bin of 1024 flat positions
  const int blk  = (p0 >> 6) & 15;    // 16 blocks of 64 per bin
  const int pg = t & 15;              // p-group (4 positions)
  const int cgl = t >> 4;             // c-group base (0..15)

  // stage x tile (256c x 64p) -> LDS [p][c] bf16 (swizzled), + fp32 partial sums
  #pragma unroll
  for (int i = 0; i < 4; ++i){
    const int c0 = (i*16 + cgl) * 4;
    const int pl = pg * 4;
    float v[4][4];
    #pragma unroll
    for (int ci = 0; ci < 4; ++ci){
      float4 q = *(const float4*)(xb + (size_t)(c0 + ci)*HWP + p0 + pl);
      v[ci][0]=q.x; v[ci][1]=q.y; v[ci][2]=q.z; v[ci][3]=q.w;
    }
    #pragma unroll
    for (int pj = 0; pj < 4; ++pj){
      const int p = pl + pj;
      unsigned off = (unsigned)(p*512 + c0*2) ^ ((unsigned)(p & 7) << 4);
      ushort4 pk;
      pk.x = f2bf(v[0][pj]); pk.y = f2bf(v[1][pj]);
      pk.z = f2bf(v[2][pj]); pk.w = f2bf(v[3][pj]);
      *(ushort4*)((char*)xlds + off) = pk;
    }
    #pragma unroll
    for (int ci = 0; ci < 4; ++ci){
      float s = v[ci][0] + v[ci][1] + v[ci][2] + v[ci][3];
      s += __shfl_xor(s, 1); s += __shfl_xor(s, 2);
      s += __shfl_xor(s, 4); s += __shfl_xor(s, 8);
      if ((lane & 15) == 0){
        xpart[(((size_t)b*9 + binj)*16 + blk)*CCH + (c0 + ci)] = s;
      }
    }
  }
  __syncthreads();

  f32x4 acc[4][4];
  f32x4 zz = {0.f,0.f,0.f,0.f};
  #pragma unroll
  for (int i2=0;i2<4;++i2){
    #pragma unroll
    for (int j2=0;j2<4;++j2) acc[i2][j2] = zz;
  }
  gemm_core(wxb, xlds, acc, lane, wave*64);

  const int g = lane >> 4, r = lane & 15;
  #pragma unroll
  for (int mf = 0; mf < 4; ++mf){
    const int o = wave*64 + mf*16 + 4*g;
    float b0 = bx[o], b1 = bx[o+1], b2 = bx[o+2], b3 = bx[o+3];
    #pragma unroll
    for (int nf = 0; nf < 4; ++nf){
      const int p = p0 + nf*16 + r;
      ushort4 pk;
      pk.x = f2bf(acc[mf][nf][0] + b0);
      pk.y = f2bf(acc[mf][nf][1] + b1);
      pk.z = f2bf(acc[mf][nf][2] + b2);
      pk.w = f2bf(acc[mf][nf][3] + b3);
      *(ushort4*)(xp + ((size_t)b*HWP + p)*CCH + o) = pk;   // [b][p][o] bf16
    }
  }
}

// ---------------- K2a: pooled[b,j,o] = gelu( w_kp @ xbar + b_kp ) ----------------
__global__ __launch_bounds__(256) void k2a_pooled(const float* __restrict__ xpart,
    const float* __restrict__ wkp, const float* __restrict__ bkp,
    float* __restrict__ pooledg){
  const int j = blockIdx.x, b = blockIdx.y, t = threadIdx.x;
  __shared__ float xbar[256];
  __shared__ float wch[256][65];
  const float* xp0 = xpart + (((size_t)b*9 + j)*16)*CCH;
  float s = 0.f;
  #pragma unroll
  for (int blk = 0; blk < 16; ++blk) s += xp0[blk*CCH + t];
  xbar[t] = s * (1.0f/1024.0f);
  float acc = bkp[t];
  for (int ch = 0; ch < 4; ++ch){
    __syncthreads();
    for (int u = t; u < 256*64; u += 256){
      wch[u >> 6][u & 63] = wkp[(size_t)(u >> 6)*CCH + ch*64 + (u & 63)];
    }
    __syncthreads();
    #pragma unroll
    for (int c = 0; c < 64; ++c) acc += wch[t][c] * xbar[ch*64 + c];
  }
  // jax.nn.gelu default: tanh approximation
  float x3 = acc*acc*acc;
  float tg = tanhf(0.7978845608028654f*(acc + 0.044715f*x3));
  pooledg[((size_t)b*9 + j)*CCH + t] = 0.5f*acc*(1.0f + tg);
}

// ---------------- K2b: ker[b,j',c] (lateral inhibition applied) ----------------
__global__ void k2b_ker(const float* __restrict__ pooledg, const float* __restrict__ wkg,
                        const float* __restrict__ bkg, const float* __restrict__ dctrl,
                        float* __restrict__ kerg){
  const int b = blockIdx.x, c = threadIdx.x;
  float pl[9];
  #pragma unroll
  for (int k = 0; k < 9; ++k) pl[k] = pooledg[((size_t)b*9 + k)*CCH + c];
  float kv[9]; float m = 0.f;
  #pragma unroll
  for (int jp = 0; jp < 9; ++jp){
    float s2 = bkg[jp];
    #pragma unroll
    for (int k = 0; k < 9; ++k) s2 += pl[k] * wkg[jp*9 + k];   // einsum 'bck,jk->bcj'
    kv[jp] = s2; m += s2;
  }
  m *= (1.0f/9.0f);
  float f = 1.0f / (1.0f + expf(-dctrl[c]));
  #pragma unroll
  for (int jp = 0; jp < 9; ++jp) kerg[((size_t)b*9 + jp)*CCH + c] = kv[jp] - f*m;
}

// ---------------- K3: dynamic depthwise 3x3 + out projection ----------------
__global__ __launch_bounds__(256) void k3_conv(const unsigned short* __restrict__ xp,
    const unsigned short* __restrict__ wpb, const float* __restrict__ bp,
    const float* __restrict__ kerg, float* __restrict__ out){
  const int tile = blockIdx.x, b = blockIdx.y;
  const int th0 = (tile / 12) * 8, tw0 = (tile % 12) * 8;   // 8x8 spatial tile
  const int t = threadIdx.x, lane = t & 63, wave = t >> 6;
  __shared__ __align__(16) unsigned short halo[100*128];    // 10x10 pos x 128c chunk
  __shared__ __align__(16) unsigned short ylds[64*256];     // y tile [p][c] swizzled
  __shared__ __align__(16) float kl[9][256];

  for (int u = t; u < 9*256; u += 256)
    kl[u >> 8][u & 255] = kerg[((size_t)b*9 + (u >> 8))*CCH + (u & 255)];

  const unsigned short* xpb = xp + (size_t)b * HWP * CCH;
  const int p = t & 63, dh = p >> 3, dw = p & 7;
  const int clb = (t >> 6) * 32;          // this thread's 32 channels within chunk

  for (int chunk = 0; chunk < 2; ++chunk){
    __syncthreads();
    // stage halo chunk: 100 positions x 128 c (zero-padded at image borders)
    for (int u = t; u < 1600; u += 256){
      const int pos = u >> 4, w16 = u & 15;
      const int rr = pos / 10, cc = pos % 10;
      const int hh = th0 + rr - 1, ww = tw0 + cc - 1;
      uint4 val = {0u,0u,0u,0u};
      if (hh >= 0 && hh < IMGDIM && ww >= 0 && ww < IMGDIM)
        val = *(const uint4*)(xpb + ((size_t)(hh*IMGDIM + ww))*CCH + chunk*128 + w16*8);
      unsigned off = (unsigned)(pos*256 + w16*16) ^ ((unsigned)(pos & 7) << 4);
      *(uint4*)((char*)halo + off) = val;
    }
    __syncthreads();
    // depthwise conv for this thread's (p, 32 channels)
    #pragma unroll
    for (int ci = 0; ci < 4; ++ci){
      const int cl = clb + ci*8;          // within chunk
      const int cg = chunk*128 + cl;      // global channel
      float a8[8] = {0,0,0,0,0,0,0,0};
      #pragma unroll
      for (int tap = 0; tap < 9; ++tap){
        const int pos = (dh + tap/3)*10 + (dw + tap%3);
        unsigned hof = (unsigned)(pos*256 + cl*2) ^ ((unsigned)(pos & 7) << 4);
        union { uint4 q; unsigned short u16[8]; } hv;
        hv.q = *(const uint4*)((const char*)halo + hof);
        const float4* kp4 = (const float4*)&kl[tap][cg];
        float4 ka = kp4[0], kb = kp4[1];
        a8[0] += bf2f(hv.u16[0]) * ka.x;
        a8[1] += bf2f(hv.u16[1]) * ka.y;
        a8[2] += bf2f(hv.u16[2]) * ka.z;
        a8[3] += bf2f(hv.u16[3]) * ka.w;
        a8[4] += bf2f(hv.u16[4]) * kb.x;
        a8[5] += bf2f(hv.u16[5]) * kb.y;
        a8[6] += bf2f(hv.u16[6]) * kb.z;
        a8[7] += bf2f(hv.u16[7]) * kb.w;
      }
      unsigned pk[4];
      #pragma unroll
      for (int e = 0; e < 4; ++e)
        pk[e] = (unsigned)f2bf(a8[2*e]) | ((unsigned)f2bf(a8[2*e+1]) << 16);
      unsigned yoff = (unsigned)(p*512 + cg*2) ^ ((unsigned)(p & 7) << 4);
      *(uint4*)((char*)ylds + yoff) = *(uint4*)pk;
    }
  }
  __syncthreads();

  f32x4 acc[4][4];
  f32x4 zz = {0.f,0.f,0.f,0.f};
  #pragma unroll
  for (int i2=0;i2<4;++i2){
    #pragma unroll
    for (int j2=0;j2<4;++j2) acc[i2][j2] = zz;
  }
  gemm_core(wpb, ylds, acc, lane, wave*64);

  const int g = lane >> 4, r = lane & 15;
  #pragma unroll
  for (int mf = 0; mf < 4; ++mf){
    const int o = wave*64 + mf*16 + 4*g;
    float b0 = bp[o], b1 = bp[o+1], b2 = bp[o+2], b3 = bp[o+3];
    #pragma unroll
    for (int nf = 0; nf < 4; ++nf){
      const int pl2 = nf*16 + r;
      const int hh = th0 + (pl2 >> 3), ww = tw0 + (pl2 & 7);
      const size_t pix = (size_t)hh*IMGDIM + ww;
      out[((size_t)b*CCH + o + 0)*HWP + pix] = acc[mf][nf][0] + b0;
      out[((size_t)b*CCH + o + 1)*HWP + pix] = acc[mf][nf][1] + b1;
      out[((size_t)b*CCH + o + 2)*HWP + pix] = acc[mf][nf][2] + b2;
      out[((size_t)b*CCH + o + 3)*HWP + pix] = acc[mf][nf][3] + b3;
    }
  }
}

extern "C" void kernel_launch(void* const* d_in, const int* in_sizes, int n_in,
                              void* d_out, int out_size, void* d_ws, size_t ws_size,
                              hipStream_t stream){
  const float* x   = (const float*)d_in[0];
  const float* wxp = (const float*)d_in[1];
  const float* bxp = (const float*)d_in[2];
  const float* wpr = (const float*)d_in[3];
  const float* bpr = (const float*)d_in[4];
  const float* wkp = (const float*)d_in[5];
  const float* bkp = (const float*)d_in[6];
  const float* wkg = (const float*)d_in[7];
  const float* bkg = (const float*)d_in[8];
  const float* dct = (const float*)d_in[9];

  char* ws = (char*)d_ws;
  unsigned short* xp    = (unsigned short*)(ws);              // 16*9216*256*2 = 75,497,472 B
  float*          xpart = (float*)(ws + 75497472);            // 16*9*16*256*4 = 2,359,296 B
  float*          pooled= (float*)(ws + 77856768);            // 16*9*256*4    =   147,456 B
  float*          kerg  = (float*)(ws + 78004224);            // 16*9*256*4    =   147,456 B
  unsigned short* wxb   = (unsigned short*)(ws + 78151680);   // 65536*2       =   131,072 B
  unsigned short* wpb   = (unsigned short*)(ws + 78282752);   // 65536*2       =   131,072 B
  float* o = (float*)d_out;

  k0_convert<<<256, 256, 0, stream>>>(wxp, wpr, wxb, wpb);
  k1_xproj<<<dim3(144,16), 256, 0, stream>>>(x, wxb, bxp, xp, xpart);
  k2a_pooled<<<dim3(9,16), 256, 0, stream>>>(xpart, wkp, bkp, pooled);
  k2b_ker<<<16, 256, 0, stream>>>(pooled, wkg, bkg, dct, kerg);
  k3_conv<<<dim3(144,16), 256, 0, stream>>>(xp, wpb, bpr, kerg, o);
}

// Round 2
// 238.716 us; speedup vs baseline: 1.1644x; 1.1644x over previous
//
#include <hip/hip_runtime.h>

#define CCH 256
#define HWP 9216
#define IMGDIM 96

typedef __attribute__((ext_vector_type(8))) short s16x8;
typedef __attribute__((ext_vector_type(4))) float f32x4;

__device__ __forceinline__ unsigned short f2bf(float f){
  unsigned u = __float_as_uint(f);
  u += 0x7fffu + ((u >> 16) & 1u);
  return (unsigned short)(u >> 16);
}
__device__ __forceinline__ float bf2f(unsigned short h){
  return __uint_as_float(((unsigned)h) << 16);
}

// ---------------- K0: convert the two projection weights to bf16 ----------------
__global__ void k0_convert(const float* __restrict__ wx, const float* __restrict__ wp,
                           unsigned short* __restrict__ wxb, unsigned short* __restrict__ wpb){
  int i = blockIdx.x * 256 + threadIdx.x;   // 65536 total
  wxb[i] = f2bf(wx[i]);
  wpb[i] = f2bf(wp[i]);
}

// ---------------- shared GEMM core ----------------
// D(256o x 64p) = W(256x256) * X(256c x 64p).
// A = wbf row-major [o][c] bf16 (global, L2-resident).
// B = lds tile [p][c] bf16, byte addr swizzled: addr ^= ((p&7)<<4).
// Same k-slot (g*8+j) for both operands; C/D: col=lane&15, row=4*(lane>>4)+reg.
__device__ __forceinline__ void gemm_core(const unsigned short* __restrict__ wbf,
                                          const unsigned short* lds_x,
                                          f32x4 acc[4][4], int lane, int obase){
  const int g = lane >> 4, r = lane & 15;
  #pragma unroll
  for (int k0 = 0; k0 < 256; k0 += 32){
    s16x8 afr[4], bfr[4];
    #pragma unroll
    for (int nf = 0; nf < 4; ++nf){
      int p = nf*16 + r;
      unsigned off = (unsigned)(p*512 + (k0 + g*8)*2) ^ ((unsigned)(p & 7) << 4);
      bfr[nf] = *(const s16x8*)((const char*)lds_x + off);
    }
    #pragma unroll
    for (int mf = 0; mf < 4; ++mf){
      afr[mf] = *(const s16x8*)(wbf + (size_t)(obase + mf*16 + r)*CCH + k0 + g*8);
    }
    #pragma unroll
    for (int mf = 0; mf < 4; ++mf){
      #pragma unroll
      for (int nf = 0; nf < 4; ++nf){
        acc[mf][nf] = __builtin_amdgcn_mfma_f32_16x16x32_bf16(afr[mf], bfr[nf], acc[mf][nf], 0, 0, 0);
      }
    }
  }
}

// ---------------- K1: xp = w_xproj * x (+bias), plus xbar partial sums ----------------
// xp stored [b][p][o] bf16 (coalesced via LDS transpose epilogue).
__global__ __launch_bounds__(256) void k1_xproj(const float* __restrict__ x,
    const unsigned short* __restrict__ wxb, const float* __restrict__ bx,
    unsigned short* __restrict__ xp, float* __restrict__ xpart){
  const int tile = blockIdx.x, b = blockIdx.y;
  const int p0 = tile * 64;
  const int t = threadIdx.x;
  const int lane = t & 63, wave = t >> 6;
  __shared__ __align__(16) unsigned short xlds[64*256];

  const float* xb = x + (size_t)b * CCH * HWP;
  const int binj = p0 >> 10;
  const int blk  = (p0 >> 6) & 15;
  const int pg = t & 15;
  const int cgl = t >> 4;

  #pragma unroll
  for (int i = 0; i < 4; ++i){
    const int c0 = (i*16 + cgl) * 4;
    const int pl = pg * 4;
    float v[4][4];
    #pragma unroll
    for (int ci = 0; ci < 4; ++ci){
      float4 q = *(const float4*)(xb + (size_t)(c0 + ci)*HWP + p0 + pl);
      v[ci][0]=q.x; v[ci][1]=q.y; v[ci][2]=q.z; v[ci][3]=q.w;
    }
    #pragma unroll
    for (int pj = 0; pj < 4; ++pj){
      const int p = pl + pj;
      unsigned off = (unsigned)(p*512 + c0*2) ^ ((unsigned)(p & 7) << 4);
      ushort4 pk;
      pk.x = f2bf(v[0][pj]); pk.y = f2bf(v[1][pj]);
      pk.z = f2bf(v[2][pj]); pk.w = f2bf(v[3][pj]);
      *(ushort4*)((char*)xlds + off) = pk;
    }
    #pragma unroll
    for (int ci = 0; ci < 4; ++ci){
      float s = v[ci][0] + v[ci][1] + v[ci][2] + v[ci][3];
      s += __shfl_xor(s, 1); s += __shfl_xor(s, 2);
      s += __shfl_xor(s, 4); s += __shfl_xor(s, 8);
      if ((lane & 15) == 0){
        xpart[(((size_t)b*9 + binj)*16 + blk)*CCH + (c0 + ci)] = s;
      }
    }
  }
  __syncthreads();

  f32x4 acc[4][4];
  f32x4 zz = {0.f,0.f,0.f,0.f};
  #pragma unroll
  for (int i2=0;i2<4;++i2){
    #pragma unroll
    for (int j2=0;j2<4;++j2) acc[i2][j2] = zz;
  }
  gemm_core(wxb, xlds, acc, lane, wave*64);

  // ---- epilogue: acc -> bf16 -> xlds [p][o] (swizzled) -> linear global stores ----
  __syncthreads();   // all waves done reading xlds
  {
    const int g = lane >> 4, r = lane & 15;
    #pragma unroll
    for (int mf = 0; mf < 4; ++mf){
      const int o = wave*64 + mf*16 + 4*g;
      float b0 = bx[o], b1 = bx[o+1], b2 = bx[o+2], b3 = bx[o+3];
      #pragma unroll
      for (int nf = 0; nf < 4; ++nf){
        const int p = nf*16 + r;
        unsigned off = (unsigned)(p*512 + o*2) ^ ((unsigned)(p & 7) << 4);
        ushort4 pk;
        pk.x = f2bf(acc[mf][nf][0] + b0);
        pk.y = f2bf(acc[mf][nf][1] + b1);
        pk.z = f2bf(acc[mf][nf][2] + b2);
        pk.w = f2bf(acc[mf][nf][3] + b3);
        *(ushort4*)((char*)xlds + off) = pk;
      }
    }
  }
  __syncthreads();
  {
    const size_t gbase = ((size_t)b*HWP + p0)*CCH;
    #pragma unroll
    for (int it = 0; it < 8; ++it){
      const unsigned u = it*256 + t;            // 16B unit
      const unsigned p = u >> 5;
      const unsigned srcoff = (u*16u) ^ ((p & 7) << 4);
      uint4 v = *(const uint4*)((const char*)xlds + srcoff);
      *(uint4*)(xp + gbase + (size_t)u*8) = v;
    }
  }
}

// ---------------- K2a: pooled[b,j,o] = gelu( w_kp @ xbar + b_kp ) ----------------
__global__ __launch_bounds__(256) void k2a_pooled(const float* __restrict__ xpart,
    const float* __restrict__ wkp, const float* __restrict__ bkp,
    float* __restrict__ pooledg){
  const int j = blockIdx.x, b = blockIdx.y, t = threadIdx.x;
  __shared__ float xbar[256];
  __shared__ float wch[256][65];
  const float* xp0 = xpart + (((size_t)b*9 + j)*16)*CCH;
  float s = 0.f;
  #pragma unroll
  for (int blk = 0; blk < 16; ++blk) s += xp0[blk*CCH + t];
  xbar[t] = s * (1.0f/1024.0f);
  float acc = bkp[t];
  for (int ch = 0; ch < 4; ++ch){
    __syncthreads();
    for (int u = t; u < 256*64; u += 256){
      wch[u >> 6][u & 63] = wkp[(size_t)(u >> 6)*CCH + ch*64 + (u & 63)];
    }
    __syncthreads();
    #pragma unroll
    for (int c = 0; c < 64; ++c) acc += wch[t][c] * xbar[ch*64 + c];
  }
  float x3 = acc*acc*acc;
  float tg = tanhf(0.7978845608028654f*(acc + 0.044715f*x3));
  pooledg[((size_t)b*9 + j)*CCH + t] = 0.5f*acc*(1.0f + tg);
}

// ---------------- K2b: ker[b,j',c] (lateral inhibition applied) ----------------
__global__ void k2b_ker(const float* __restrict__ pooledg, const float* __restrict__ wkg,
                        const float* __restrict__ bkg, const float* __restrict__ dctrl,
                        float* __restrict__ kerg){
  const int b = blockIdx.x, c = threadIdx.x;
  float pl[9];
  #pragma unroll
  for (int k = 0; k < 9; ++k) pl[k] = pooledg[((size_t)b*9 + k)*CCH + c];
  float kv[9]; float m = 0.f;
  #pragma unroll
  for (int jp = 0; jp < 9; ++jp){
    float s2 = bkg[jp];
    #pragma unroll
    for (int k = 0; k < 9; ++k) s2 += pl[k] * wkg[jp*9 + k];
    kv[jp] = s2; m += s2;
  }
  m *= (1.0f/9.0f);
  float f = 1.0f / (1.0f + expf(-dctrl[c]));
  #pragma unroll
  for (int jp = 0; jp < 9; ++jp) kerg[((size_t)b*9 + jp)*CCH + c] = kv[jp] - f*m;
}

// ---------------- K3a: dynamic depthwise 3x3 -> y [b][p][o] bf16 ----------------
// 4 threads per position (channel-contiguous stores), 2 channel-chunks of 128.
__global__ __launch_bounds__(256) void k3a_dw(const unsigned short* __restrict__ xp,
    const float* __restrict__ kerg, unsigned short* __restrict__ y){
  const int tile = blockIdx.x, b = blockIdx.y;
  const int th0 = (tile / 12) * 8, tw0 = (tile % 12) * 8;
  const int t = threadIdx.x;
  __shared__ __align__(16) unsigned short halo[100*128];   // 25.6 KB (per chunk)
  __shared__ float kl[9][256];                             // 9 KB

  for (int u = t; u < 9*256; u += 256)
    kl[u >> 8][u & 255] = kerg[((size_t)b*9 + (u >> 8))*CCH + (u & 255)];

  const unsigned short* xpb = xp + (size_t)b * HWP * CCH;
  unsigned short* yb = y + (size_t)b * HWP * CCH;
  const int p = t >> 2;                 // 0..63 tile position
  const int dh = p >> 3, dw = p & 7;
  const int cl = (t & 3) * 8;           // 8-ch base; ci stride 32
  const size_t pout = (size_t)((th0 + dh)*IMGDIM + (tw0 + dw))*CCH;

  for (int chunk = 0; chunk < 2; ++chunk){
    __syncthreads();
    for (int u = t; u < 1600; u += 256){
      const int pos = u >> 4, w16 = u & 15;
      const int rr = pos / 10, cc = pos % 10;
      const int hh = th0 + rr - 1, ww = tw0 + cc - 1;
      uint4 val = {0u,0u,0u,0u};
      if (hh >= 0 && hh < IMGDIM && ww >= 0 && ww < IMGDIM)
        val = *(const uint4*)(xpb + ((size_t)(hh*IMGDIM + ww))*CCH + chunk*128 + w16*8);
      unsigned off = (unsigned)(pos*256 + w16*16) ^ ((unsigned)(pos & 7) << 4);
      *(uint4*)((char*)halo + off) = val;
    }
    __syncthreads();
    #pragma unroll
    for (int ci = 0; ci < 4; ++ci){
      const int c = cl + ci*32;          // within chunk
      const int cg = chunk*128 + c;      // global channel
      float a8[8] = {0,0,0,0,0,0,0,0};
      #pragma unroll
      for (int tap = 0; tap < 9; ++tap){
        const int pos = (dh + tap/3)*10 + (dw + tap%3);
        unsigned hof = (unsigned)(pos*256 + c*2) ^ ((unsigned)(pos & 7) << 4);
        union { uint4 q; unsigned short u16[8]; } hv;
        hv.q = *(const uint4*)((const char*)halo + hof);
        const float4* kp4 = (const float4*)&kl[tap][cg];
        float4 ka = kp4[0], kb = kp4[1];
        a8[0] += bf2f(hv.u16[0]) * ka.x;
        a8[1] += bf2f(hv.u16[1]) * ka.y;
        a8[2] += bf2f(hv.u16[2]) * ka.z;
        a8[3] += bf2f(hv.u16[3]) * ka.w;
        a8[4] += bf2f(hv.u16[4]) * kb.x;
        a8[5] += bf2f(hv.u16[5]) * kb.y;
        a8[6] += bf2f(hv.u16[6]) * kb.z;
        a8[7] += bf2f(hv.u16[7]) * kb.w;
      }
      unsigned pk[4];
      #pragma unroll
      for (int e = 0; e < 4; ++e)
        pk[e] = (unsigned)f2bf(a8[2*e]) | ((unsigned)f2bf(a8[2*e+1]) << 16);
      *(uint4*)(yb + pout + cg) = *(uint4*)pk;
    }
  }
}

// ---------------- K3b: out = w_proj * y (+bias), fp32 NCHW ----------------
__global__ __launch_bounds__(256) void k3b_proj(const unsigned short* __restrict__ y,
    const unsigned short* __restrict__ wpb, const float* __restrict__ bp,
    float* __restrict__ out){
  const int tile = blockIdx.x, b = blockIdx.y;
  const int p0 = tile * 64;
  const int t = threadIdx.x, lane = t & 63, wave = t >> 6;
  __shared__ __align__(16) unsigned short ylds[64*256];    // 32 KB
  const unsigned short* yb = y + (size_t)b * HWP * CCH;

  #pragma unroll
  for (int it = 0; it < 8; ++it){
    const unsigned u = it*256 + t;            // dest 16B unit (linear)
    const unsigned p = u >> 5;
    const unsigned c16 = (u & 31) ^ (p & 7);  // inverse-swizzled source unit
    uint4 v = *(const uint4*)(yb + (size_t)(p0 + p)*CCH + c16*8);
    *(uint4*)((char*)ylds + (size_t)u*16) = v;
  }
  __syncthreads();

  f32x4 acc[4][4];
  f32x4 zz = {0.f,0.f,0.f,0.f};
  #pragma unroll
  for (int i2=0;i2<4;++i2){
    #pragma unroll
    for (int j2=0;j2<4;++j2) acc[i2][j2] = zz;
  }
  gemm_core(wpb, ylds, acc, lane, wave*64);

  const int g = lane >> 4, r = lane & 15;
  #pragma unroll
  for (int mf = 0; mf < 4; ++mf){
    const int o = wave*64 + mf*16 + 4*g;
    float b0 = bp[o], b1 = bp[o+1], b2 = bp[o+2], b3 = bp[o+3];
    #pragma unroll
    for (int nf = 0; nf < 4; ++nf){
      const int pp = p0 + nf*16 + r;
      out[((size_t)b*CCH + o + 0)*HWP + pp] = acc[mf][nf][0] + b0;
      out[((size_t)b*CCH + o + 1)*HWP + pp] = acc[mf][nf][1] + b1;
      out[((size_t)b*CCH + o + 2)*HWP + pp] = acc[mf][nf][2] + b2;
      out[((size_t)b*CCH + o + 3)*HWP + pp] = acc[mf][nf][3] + b3;
    }
  }
}

// ---------------- fallback fused K3 (small-ws path, known-good) ----------------
__global__ __launch_bounds__(256) void k3_conv(const unsigned short* __restrict__ xp,
    const unsigned short* __restrict__ wpb, const float* __restrict__ bp,
    const float* __restrict__ kerg, float* __restrict__ out){
  const int tile = blockIdx.x, b = blockIdx.y;
  const int th0 = (tile / 12) * 8, tw0 = (tile % 12) * 8;
  const int t = threadIdx.x, lane = t & 63, wave = t >> 6;
  __shared__ __align__(16) unsigned short halo[100*128];
  __shared__ __align__(16) unsigned short ylds[64*256];
  __shared__ __align__(16) float kl[9][256];

  for (int u = t; u < 9*256; u += 256)
    kl[u >> 8][u & 255] = kerg[((size_t)b*9 + (u >> 8))*CCH + (u & 255)];

  const unsigned short* xpb = xp + (size_t)b * HWP * CCH;
  const int p = t & 63, dh = p >> 3, dw = p & 7;
  const int clb = (t >> 6) * 32;

  for (int chunk = 0; chunk < 2; ++chunk){
    __syncthreads();
    for (int u = t; u < 1600; u += 256){
      const int pos = u >> 4, w16 = u & 15;
      const int rr = pos / 10, cc = pos % 10;
      const int hh = th0 + rr - 1, ww = tw0 + cc - 1;
      uint4 val = {0u,0u,0u,0u};
      if (hh >= 0 && hh < IMGDIM && ww >= 0 && ww < IMGDIM)
        val = *(const uint4*)(xpb + ((size_t)(hh*IMGDIM + ww))*CCH + chunk*128 + w16*8);
      unsigned off = (unsigned)(pos*256 + w16*16) ^ ((unsigned)(pos & 7) << 4);
      *(uint4*)((char*)halo + off) = val;
    }
    __syncthreads();
    #pragma unroll
    for (int ci = 0; ci < 4; ++ci){
      const int cl = clb + ci*8;
      const int cg = chunk*128 + cl;
      float a8[8] = {0,0,0,0,0,0,0,0};
      #pragma unroll
      for (int tap = 0; tap < 9; ++tap){
        const int pos = (dh + tap/3)*10 + (dw + tap%3);
        unsigned hof = (unsigned)(pos*256 + cl*2) ^ ((unsigned)(pos & 7) << 4);
        union { uint4 q; unsigned short u16[8]; } hv;
        hv.q = *(const uint4*)((const char*)halo + hof);
        const float4* kp4 = (const float4*)&kl[tap][cg];
        float4 ka = kp4[0], kb = kp4[1];
        a8[0] += bf2f(hv.u16[0]) * ka.x;
        a8[1] += bf2f(hv.u16[1]) * ka.y;
        a8[2] += bf2f(hv.u16[2]) * ka.z;
        a8[3] += bf2f(hv.u16[3]) * ka.w;
        a8[4] += bf2f(hv.u16[4]) * kb.x;
        a8[5] += bf2f(hv.u16[5]) * kb.y;
        a8[6] += bf2f(hv.u16[6]) * kb.z;
        a8[7] += bf2f(hv.u16[7]) * kb.w;
      }
      unsigned pk[4];
      #pragma unroll
      for (int e = 0; e < 4; ++e)
        pk[e] = (unsigned)f2bf(a8[2*e]) | ((unsigned)f2bf(a8[2*e+1]) << 16);
      unsigned yoff = (unsigned)(p*512 + cg*2) ^ ((unsigned)(p & 7) << 4);
      *(uint4*)((char*)ylds + yoff) = *(uint4*)pk;
    }
  }
  __syncthreads();

  f32x4 acc[4][4];
  f32x4 zz = {0.f,0.f,0.f,0.f};
  #pragma unroll
  for (int i2=0;i2<4;++i2){
    #pragma unroll
    for (int j2=0;j2<4;++j2) acc[i2][j2] = zz;
  }
  gemm_core(wpb, ylds, acc, lane, wave*64);

  const int g = lane >> 4, r = lane & 15;
  #pragma unroll
  for (int mf = 0; mf < 4; ++mf){
    const int o = wave*64 + mf*16 + 4*g;
    float b0 = bp[o], b1 = bp[o+1], b2 = bp[o+2], b3 = bp[o+3];
    #pragma unroll
    for (int nf = 0; nf < 4; ++nf){
      const int pl2 = nf*16 + r;
      const int hh = th0 + (pl2 >> 3), ww = tw0 + (pl2 & 7);
      const size_t pix = (size_t)hh*IMGDIM + ww;
      out[((size_t)b*CCH + o + 0)*HWP + pix] = acc[mf][nf][0] + b0;
      out[((size_t)b*CCH + o + 1)*HWP + pix] = acc[mf][nf][1] + b1;
      out[((size_t)b*CCH + o + 2)*HWP + pix] = acc[mf][nf][2] + b2;
      out[((size_t)b*CCH + o + 3)*HWP + pix] = acc[mf][nf][3] + b3;
    }
  }
}

extern "C" void kernel_launch(void* const* d_in, const int* in_sizes, int n_in,
                              void* d_out, int out_size, void* d_ws, size_t ws_size,
                              hipStream_t stream){
  const float* x   = (const float*)d_in[0];
  const float* wxp = (const float*)d_in[1];
  const float* bxp = (const float*)d_in[2];
  const float* wpr = (const float*)d_in[3];
  const float* bpr = (const float*)d_in[4];
  const float* wkp = (const float*)d_in[5];
  const float* bkp = (const float*)d_in[6];
  const float* wkg = (const float*)d_in[7];
  const float* bkg = (const float*)d_in[8];
  const float* dct = (const float*)d_in[9];

  char* ws = (char*)d_ws;
  unsigned short* wxb   = (unsigned short*)(ws + 0);          //   131,072
  unsigned short* wpb   = (unsigned short*)(ws + 131072);     //   131,072
  float*          xpart = (float*)(ws + 262144);              // 2,359,296
  float*          pooled= (float*)(ws + 2621440);             //   147,456
  float*          kerg  = (float*)(ws + 2768896);             //   147,456
  unsigned short* xp    = (unsigned short*)(ws + 2916352);    // 75,497,472
  unsigned short* ybuf  = (unsigned short*)(ws + 78413824);   // 75,497,472 (split path only)
  const size_t need_split = 153911296;
  float* o = (float*)d_out;

  k0_convert<<<256, 256, 0, stream>>>(wxp, wpr, wxb, wpb);
  k1_xproj<<<dim3(144,16), 256, 0, stream>>>(x, wxb, bxp, xp, xpart);
  k2a_pooled<<<dim3(9,16), 256, 0, stream>>>(xpart, wkp, bkp, pooled);
  k2b_ker<<<16, 256, 0, stream>>>(pooled, wkg, bkg, dct, kerg);
  if (ws_size >= need_split){
    k3a_dw<<<dim3(144,16), 256, 0, stream>>>(xp, kerg, ybuf);
    k3b_proj<<<dim3(144,16), 256, 0, stream>>>(ybuf, wpb, bpr, o);
  } else {
    k3_conv<<<dim3(144,16), 256, 0, stream>>>(xp, wpb, bpr, kerg, o);
  }
}

// Round 3
// 235.707 us; speedup vs baseline: 1.1793x; 1.0128x over previous
//
#include <hip/hip_runtime.h>

#define CCH 256
#define HWP 9216
#define IMGDIM 96

typedef __attribute__((ext_vector_type(8))) short s16x8;
typedef __attribute__((ext_vector_type(4))) float f32x4;

__device__ __forceinline__ unsigned short f2bf(float f){
  unsigned u = __float_as_uint(f);
  u += 0x7fffu + ((u >> 16) & 1u);
  return (unsigned short)(u >> 16);
}
__device__ __forceinline__ float bf2f(unsigned short h){
  return __uint_as_float(((unsigned)h) << 16);
}

// ---------------- K0: convert the two projection weights to bf16 ----------------
__global__ void k0_convert(const float* __restrict__ wx, const float* __restrict__ wp,
                           unsigned short* __restrict__ wxb, unsigned short* __restrict__ wpb){
  int i = blockIdx.x * 256 + threadIdx.x;   // 65536 total
  wxb[i] = f2bf(wx[i]);
  wpb[i] = f2bf(wp[i]);
}

// ---------------- chunked GEMM core: one 64-c chunk ----------------
// D(256o x 64p) += W[:, c0:c0+64] * B_chunk.  B chunk LDS layout: [p][c(64)] bf16,
// row = 128B, byte addr ^= ((p&7)<<4).  Same k-slot for A and B; C/D: col=lane&15,
// row=4*(lane>>4)+reg.
__device__ __forceinline__ void gemm_chunk(const unsigned short* __restrict__ wbf,
                                           const unsigned short* buf,
                                           f32x4 acc[4][4], int lane, int obase, int c0){
  const int g = lane >> 4, r = lane & 15;
  #pragma unroll
  for (int kk = 0; kk < 2; ++kk){
    const int kc = kk*32 + g*8;
    s16x8 afr[4], bfr[4];
    #pragma unroll
    for (int nf = 0; nf < 4; ++nf){
      const int p = nf*16 + r;
      unsigned off = (unsigned)(p*128 + kc*2) ^ ((unsigned)(p & 7) << 4);
      bfr[nf] = *(const s16x8*)((const char*)buf + off);
    }
    #pragma unroll
    for (int mf = 0; mf < 4; ++mf)
      afr[mf] = *(const s16x8*)(wbf + (size_t)(obase + mf*16 + r)*CCH + c0 + kc);
    #pragma unroll
    for (int mf = 0; mf < 4; ++mf){
      #pragma unroll
      for (int nf = 0; nf < 4; ++nf){
        acc[mf][nf] = __builtin_amdgcn_mfma_f32_16x16x32_bf16(afr[mf], bfr[nf], acc[mf][nf], 0, 0, 0);
      }
    }
  }
}

// ---------------- K1 helpers ----------------
__device__ __forceinline__ void k1_load(const float* __restrict__ xb, int p0, int c0,
                                        int pg, int cgl, float v[4][4]){
  #pragma unroll
  for (int ci = 0; ci < 4; ++ci){
    float4 q = *(const float4*)(xb + (size_t)(c0 + cgl*4 + ci)*HWP + p0 + pg*4);
    v[ci][0]=q.x; v[ci][1]=q.y; v[ci][2]=q.z; v[ci][3]=q.w;
  }
}
__device__ __forceinline__ void k1_store(unsigned short* buf, int pg, int cgl, float v[4][4],
                                         float* __restrict__ xpart, int c0, int lane, int bbase){
  #pragma unroll
  for (int pj = 0; pj < 4; ++pj){
    const int p = pg*4 + pj;
    unsigned off = (unsigned)(p*128 + cgl*8) ^ ((unsigned)(p & 7) << 4);
    ushort4 pk;
    pk.x = f2bf(v[0][pj]); pk.y = f2bf(v[1][pj]);
    pk.z = f2bf(v[2][pj]); pk.w = f2bf(v[3][pj]);
    *(ushort4*)((char*)buf + off) = pk;
  }
  #pragma unroll
  for (int ci = 0; ci < 4; ++ci){
    float s = v[ci][0] + v[ci][1] + v[ci][2] + v[ci][3];
    s += __shfl_xor(s, 1); s += __shfl_xor(s, 2);
    s += __shfl_xor(s, 4); s += __shfl_xor(s, 8);
    if ((lane & 15) == 0) xpart[bbase + c0 + cgl*4 + ci] = s;
  }
}

// ---------------- K1: xp = w_xproj * x (+bias), plus xbar partial sums ----------------
// K-chunked, double-buffered LDS (2 x 8KB).  xp stored [b][p][o] bf16.
__global__ __launch_bounds__(256) void k1_xproj(const float* __restrict__ x,
    const unsigned short* __restrict__ wxb, const float* __restrict__ bx,
    unsigned short* __restrict__ xp, float* __restrict__ xpart){
  const int tile = blockIdx.x, b = blockIdx.y;
  const int p0 = tile * 64;
  const int t = threadIdx.x, lane = t & 63, wave = t >> 6;
  __shared__ __align__(16) unsigned short xlds[2][64*64];   // 2 x 8KB

  const float* xb = x + (size_t)b * CCH * HWP;
  const int binj = p0 >> 10, blk = (p0 >> 6) & 15;
  const int bbase = (((int)b*9 + binj)*16 + blk)*CCH;
  const int pg = t & 15, cgl = t >> 4;

  float v[2][4][4];
  f32x4 acc[4][4];
  f32x4 zz = {0.f,0.f,0.f,0.f};
  #pragma unroll
  for (int i2=0;i2<4;++i2){
    #pragma unroll
    for (int j2=0;j2<4;++j2) acc[i2][j2] = zz;
  }

  // prologue: chunk 0
  k1_load(xb, p0, 0, pg, cgl, v[0]);
  k1_store(xlds[0], pg, cgl, v[0], xpart, 0, lane, bbase);

  #pragma unroll
  for (int ch = 0; ch < 4; ++ch){
    __syncthreads();
    if (ch < 3) k1_load(xb, p0, (ch+1)*64, pg, cgl, v[(ch+1)&1]);
    gemm_chunk(wxb, xlds[ch & 1], acc, lane, wave*64, ch*64);
    if (ch < 3) k1_store(xlds[(ch+1)&1], pg, cgl, v[(ch+1)&1], xpart, (ch+1)*64, lane, bbase);
  }

  // epilogue: 2 o-half passes through the 16KB buffer, then linear stores
  unsigned short* eb = &xlds[0][0];
  const int g = lane >> 4, r = lane & 15;
  #pragma unroll
  for (int h = 0; h < 2; ++h){
    __syncthreads();
    if ((wave >> 1) == h){
      const int mw = wave & 1;
      #pragma unroll
      for (int mf = 0; mf < 4; ++mf){
        const int o  = mw*64 + mf*16 + 4*g;     // within 128-half
        const int og = h*128 + o;
        float b0 = bx[og], b1 = bx[og+1], b2 = bx[og+2], b3 = bx[og+3];
        #pragma unroll
        for (int nf = 0; nf < 4; ++nf){
          const int p = nf*16 + r;
          unsigned off = (unsigned)(p*256 + o*2) ^ ((unsigned)(p & 7) << 4);
          ushort4 pk;
          pk.x = f2bf(acc[mf][nf][0] + b0);
          pk.y = f2bf(acc[mf][nf][1] + b1);
          pk.z = f2bf(acc[mf][nf][2] + b2);
          pk.w = f2bf(acc[mf][nf][3] + b3);
          *(ushort4*)((char*)eb + off) = pk;
        }
      }
    }
    __syncthreads();
    const size_t gb = ((size_t)b*HWP + p0)*CCH + h*128;
    #pragma unroll
    for (int it = 0; it < 4; ++it){
      const unsigned u = it*256 + t;          // 1024 x 16B units
      const unsigned p = u >> 4, unit = u & 15;
      const unsigned srcoff = (u*16u) ^ ((p & 7) << 4);
      uint4 val = *(const uint4*)((const char*)eb + srcoff);
      *(uint4*)(xp + gb + (size_t)p*CCH + unit*8) = val;
    }
  }
}

// ---------------- K2a: pooled[b,j,o] = gelu( w_kp @ xbar + b_kp ) ----------------
__global__ __launch_bounds__(256) void k2a_pooled(const float* __restrict__ xpart,
    const float* __restrict__ wkp, const float* __restrict__ bkp,
    float* __restrict__ pooledg){
  const int j = blockIdx.x, b = blockIdx.y, t = threadIdx.x;
  __shared__ float xbar[256];
  __shared__ float wch[256][65];
  const float* xp0 = xpart + (((size_t)b*9 + j)*16)*CCH;
  float s = 0.f;
  #pragma unroll
  for (int blk = 0; blk < 16; ++blk) s += xp0[blk*CCH + t];
  xbar[t] = s * (1.0f/1024.0f);
  float acc = bkp[t];
  for (int ch = 0; ch < 4; ++ch){
    __syncthreads();
    for (int u = t; u < 256*64; u += 256){
      wch[u >> 6][u & 63] = wkp[(size_t)(u >> 6)*CCH + ch*64 + (u & 63)];
    }
    __syncthreads();
    #pragma unroll
    for (int c = 0; c < 64; ++c) acc += wch[t][c] * xbar[ch*64 + c];
  }
  float x3 = acc*acc*acc;
  float tg = tanhf(0.7978845608028654f*(acc + 0.044715f*x3));
  pooledg[((size_t)b*9 + j)*CCH + t] = 0.5f*acc*(1.0f + tg);
}

// ---------------- K2b: ker[b,j',c] (lateral inhibition applied) ----------------
__global__ void k2b_ker(const float* __restrict__ pooledg, const float* __restrict__ wkg,
                        const float* __restrict__ bkg, const float* __restrict__ dctrl,
                        float* __restrict__ kerg){
  const int b = blockIdx.x, c = threadIdx.x;
  float pl[9];
  #pragma unroll
  for (int k = 0; k < 9; ++k) pl[k] = pooledg[((size_t)b*9 + k)*CCH + c];
  float kv[9]; float m = 0.f;
  #pragma unroll
  for (int jp = 0; jp < 9; ++jp){
    float s2 = bkg[jp];
    #pragma unroll
    for (int k = 0; k < 9; ++k) s2 += pl[k] * wkg[jp*9 + k];
    kv[jp] = s2; m += s2;
  }
  m *= (1.0f/9.0f);
  float f = 1.0f / (1.0f + expf(-dctrl[c]));
  #pragma unroll
  for (int jp = 0; jp < 9; ++jp) kerg[((size_t)b*9 + jp)*CCH + c] = kv[jp] - f*m;
}

// ---------------- K3a: dynamic depthwise 3x3 -> y [b][p][o] bf16 ----------------
// 4 channel-chunks of 64, double-buffered halo (2 x 12.8KB), issue-early/write-late.
__global__ __launch_bounds__(256) void k3a_dw(const unsigned short* __restrict__ xp,
    const float* __restrict__ kerg, unsigned short* __restrict__ y){
  const int tile = blockIdx.x, b = blockIdx.y;
  const int th0 = (tile / 12) * 8, tw0 = (tile % 12) * 8;
  const int t = threadIdx.x;
  __shared__ __align__(16) unsigned short halo[2][100*64];  // 2 x 12.8KB
  __shared__ float kl[9][256];                              // 9KB

  for (int u = t; u < 9*256; u += 256)
    kl[u >> 8][u & 255] = kerg[((size_t)b*9 + (u >> 8))*CCH + (u & 255)];

  const unsigned short* xpb = xp + (size_t)b * HWP * CCH;
  unsigned short* yb = y + (size_t)b * HWP * CCH;
  const int p = t >> 2, dh = p >> 3, dw = p & 7, q = t & 3;
  const size_t pout = (size_t)((th0 + dh)*IMGDIM + (tw0 + dw))*CCH;

  uint4 sreg[4];

  // per-thread staging units: u = i*256+t over 800 x 16B units (pos 0..99, 8 units ea.)
  #define K3A_ISSUE(CH)                                                        \
    _Pragma("unroll")                                                          \
    for (int i = 0; i < 4; ++i){                                               \
      const int u = i*256 + t;                                                 \
      if (u < 800){                                                            \
        const int pos = u >> 3, w8 = u & 7;                                    \
        const int rr = pos / 10, cc = pos % 10;                                \
        const int hh = th0 + rr - 1, ww = tw0 + cc - 1;                        \
        uint4 val = {0u,0u,0u,0u};                                             \
        if (hh >= 0 && hh < IMGDIM && ww >= 0 && ww < IMGDIM)                  \
          val = *(const uint4*)(xpb + ((size_t)(hh*IMGDIM + ww))*CCH + (CH)*64 + w8*8); \
        sreg[i] = val;                                                         \
      }                                                                        \
    }
  #define K3A_WRITE(BUF)                                                       \
    _Pragma("unroll")                                                          \
    for (int i = 0; i < 4; ++i){                                               \
      const int u = i*256 + t;                                                 \
      if (u < 800){                                                            \
        const int pos = u >> 3, w8 = u & 7;                                    \
        unsigned off = (unsigned)(pos*128 + w8*16) ^ ((unsigned)(pos & 7) << 4); \
        *(uint4*)((char*)halo[BUF] + off) = sreg[i];                           \
      }                                                                        \
    }

  K3A_ISSUE(0)
  K3A_WRITE(0)

  #pragma unroll
  for (int ch = 0; ch < 4; ++ch){
    __syncthreads();
    if (ch < 3) K3A_ISSUE(ch+1)
    // conv on halo[ch&1]
    #pragma unroll
    for (int ci = 0; ci < 2; ++ci){
      const int c = q*16 + ci*8;          // within 64-chunk
      const int cg = ch*64 + c;           // global channel
      float a8[8] = {0,0,0,0,0,0,0,0};
      #pragma unroll
      for (int tap = 0; tap < 9; ++tap){
        const int pos = (dh + tap/3)*10 + (dw + tap%3);
        unsigned hof = (unsigned)(pos*128 + c*2) ^ ((unsigned)(pos & 7) << 4);
        union { uint4 qv; unsigned short u16[8]; } hv;
        hv.qv = *(const uint4*)((const char*)halo[ch & 1] + hof);
        const float4* kp4 = (const float4*)&kl[tap][cg];
        float4 ka = kp4[0], kb = kp4[1];
        a8[0] += bf2f(hv.u16[0]) * ka.x;
        a8[1] += bf2f(hv.u16[1]) * ka.y;
        a8[2] += bf2f(hv.u16[2]) * ka.z;
        a8[3] += bf2f(hv.u16[3]) * ka.w;
        a8[4] += bf2f(hv.u16[4]) * kb.x;
        a8[5] += bf2f(hv.u16[5]) * kb.y;
        a8[6] += bf2f(hv.u16[6]) * kb.z;
        a8[7] += bf2f(hv.u16[7]) * kb.w;
      }
      unsigned pk[4];
      #pragma unroll
      for (int e = 0; e < 4; ++e)
        pk[e] = (unsigned)f2bf(a8[2*e]) | ((unsigned)f2bf(a8[2*e+1]) << 16);
      *(uint4*)(yb + pout + cg) = *(uint4*)pk;
    }
    if (ch < 3) K3A_WRITE((ch+1)&1)
  }
  #undef K3A_ISSUE
  #undef K3A_WRITE
}

// ---------------- K3b: out = w_proj * y (+bias), fp32 NCHW ----------------
// K-chunked, double-buffered LDS (2 x 8KB).
__global__ __launch_bounds__(256) void k3b_proj(const unsigned short* __restrict__ y,
    const unsigned short* __restrict__ wpb, const float* __restrict__ bp,
    float* __restrict__ out){
  const int tile = blockIdx.x, b = blockIdx.y;
  const int p0 = tile * 64;
  const int t = threadIdx.x, lane = t & 63, wave = t >> 6;
  __shared__ __align__(16) unsigned short ylds[2][64*64];   // 2 x 8KB
  const unsigned short* yb = y + (size_t)b * HWP * CCH;

  const int ug = t & 7, pg2 = t >> 3;    // 8 c-units of 8ch; 32 p-groups
  uint4 srg[2];

  #define K3B_ISSUE(CH)                                                        \
    _Pragma("unroll")                                                          \
    for (int i = 0; i < 2; ++i)                                                \
      srg[i] = *(const uint4*)(yb + (size_t)(p0 + pg2 + i*32)*CCH + (CH)*64 + ug*8);
  #define K3B_WRITE(BUF)                                                       \
    _Pragma("unroll")                                                          \
    for (int i = 0; i < 2; ++i){                                               \
      const int p = pg2 + i*32;                                                \
      unsigned off = (unsigned)(p*128 + ug*16) ^ ((unsigned)(p & 7) << 4);     \
      *(uint4*)((char*)ylds[BUF] + off) = srg[i];                              \
    }

  f32x4 acc[4][4];
  f32x4 zz = {0.f,0.f,0.f,0.f};
  #pragma unroll
  for (int i2=0;i2<4;++i2){
    #pragma unroll
    for (int j2=0;j2<4;++j2) acc[i2][j2] = zz;
  }

  K3B_ISSUE(0)
  K3B_WRITE(0)

  #pragma unroll
  for (int ch = 0; ch < 4; ++ch){
    __syncthreads();
    if (ch < 3) K3B_ISSUE(ch+1)
    gemm_chunk(wpb, ylds[ch & 1], acc, lane, wave*64, ch*64);
    if (ch < 3) K3B_WRITE((ch+1)&1)
  }
  #undef K3B_ISSUE
  #undef K3B_WRITE

  const int g = lane >> 4, r = lane & 15;
  #pragma unroll
  for (int mf = 0; mf < 4; ++mf){
    const int o = wave*64 + mf*16 + 4*g;
    float b0 = bp[o], b1 = bp[o+1], b2 = bp[o+2], b3 = bp[o+3];
    #pragma unroll
    for (int nf = 0; nf < 4; ++nf){
      const int pp = p0 + nf*16 + r;
      out[((size_t)b*CCH + o + 0)*HWP + pp] = acc[mf][nf][0] + b0;
      out[((size_t)b*CCH + o + 1)*HWP + pp] = acc[mf][nf][1] + b1;
      out[((size_t)b*CCH + o + 2)*HWP + pp] = acc[mf][nf][2] + b2;
      out[((size_t)b*CCH + o + 3)*HWP + pp] = acc[mf][nf][3] + b3;
    }
  }
}

extern "C" void kernel_launch(void* const* d_in, const int* in_sizes, int n_in,
                              void* d_out, int out_size, void* d_ws, size_t ws_size,
                              hipStream_t stream){
  const float* x   = (const float*)d_in[0];
  const float* wxp = (const float*)d_in[1];
  const float* bxp = (const float*)d_in[2];
  const float* wpr = (const float*)d_in[3];
  const float* bpr = (const float*)d_in[4];
  const float* wkp = (const float*)d_in[5];
  const float* bkp = (const float*)d_in[6];
  const float* wkg = (const float*)d_in[7];
  const float* bkg = (const float*)d_in[8];
  const float* dct = (const float*)d_in[9];

  char* ws = (char*)d_ws;
  unsigned short* wxb   = (unsigned short*)(ws + 0);          //   131,072
  unsigned short* wpb   = (unsigned short*)(ws + 131072);     //   131,072
  float*          xpart = (float*)(ws + 262144);              // 2,359,296
  float*          pooled= (float*)(ws + 2621440);             //   147,456
  float*          kerg  = (float*)(ws + 2768896);             //   147,456
  unsigned short* xp    = (unsigned short*)(ws + 2916352);    // 75,497,472
  unsigned short* ybuf  = (unsigned short*)(ws + 78413824);   // 75,497,472
  float* o = (float*)d_out;

  k0_convert<<<256, 256, 0, stream>>>(wxp, wpr, wxb, wpb);
  k1_xproj<<<dim3(144,16), 256, 0, stream>>>(x, wxb, bxp, xp, xpart);
  k2a_pooled<<<dim3(9,16), 256, 0, stream>>>(xpart, wkp, bkp, pooled);
  k2b_ker<<<16, 256, 0, stream>>>(pooled, wkg, bkg, dct, kerg);
  k3a_dw<<<dim3(144,16), 256, 0, stream>>>(xp, kerg, ybuf);
  k3b_proj<<<dim3(144,16), 256, 0, stream>>>(ybuf, wpb, bpr, o);
}